// Round 4
// baseline (427.695 us; speedup 1.0000x reference)
//
#include <hip/hip_runtime.h>

// S2V GNN step:
//  out[n][j] = relu( base[n][j] + relu( sw[n]*vs[j] + sum_{e:src=n} hc2[dst_e][j] ) )
//  base = p*a + q*b + h_mu          (p,q = relu(+-x))
//  hc2  = h_mu@W4c.T + p*va + q*vb  (stored bf16)
//  sw   = sum of ew over out-edges  (carried in the counting atomic, 2^20 fixed point)

#define CAP 96     // bucket capacity; deg ~ Poisson(32), P(deg>=96) ~ 1e-19/node
#define NPB 4      // nodes (waves) per 256-thread block in k_final

// ---------- K0: tiny weight-derived vectors ----------
__global__ void k_prep(const float* __restrict__ W1, const float* __restrict__ W2,
                       const float* __restrict__ W4,
                       float* __restrict__ a, float* __restrict__ b,
                       float* __restrict__ va, float* __restrict__ vb,
                       float* __restrict__ vs) {
    __shared__ float sa[64], sb[64], sw[64];
    int j = threadIdx.x;  // 0..63
    float w1 = W1[j], w2 = W2[j];
    sa[j] = fmaxf(w1, 0.f);
    sb[j] = fmaxf(-w1, 0.f);
    sw[j] = fmaxf(w2, 0.f);
    __syncthreads();
    float s1 = 0.f, s2 = 0.f, s3 = 0.f;
#pragma unroll
    for (int o = 0; o < 64; ++o) {
        float w4a = W4[j * 192 + o];
        float w4b = W4[j * 192 + 64 + o];
        s1 += w4a * sa[o];
        s2 += w4a * sb[o];
        s3 += w4b * sw[o];
    }
    a[j] = sa[j]; b[j] = sb[j];
    va[j] = s1; vb[j] = s2; vs[j] = s3;
}

// ---------- K1 (fused): role-interleaved bucket-scatter + hmu GEMM ----------
// every 8th block (id%8==7) runs the hmu GEMM; the rest scatter edges.
// Overlap: scatter is memory/atomic-bound, GEMM is VALU/LDS-bound.
__global__ void __launch_bounds__(256) k_mid(
    const float* __restrict__ mu, const float* __restrict__ W3, const float* __restrict__ W4,
    const float* __restrict__ x,
    const float* __restrict__ a, const float* __restrict__ b,
    const float* __restrict__ va, const float* __restrict__ vb,
    float* __restrict__ base, unsigned short* __restrict__ hc2,
    const int* __restrict__ ei, const float* __restrict__ ew,
    unsigned long long* __restrict__ cs, int* __restrict__ slots,
    int n_nodes, int E) {
    __shared__ float sW3[64 * 65];
    __shared__ float sW4c[64 * 65];
    __shared__ float smu[NPB][64];
    __shared__ float srow[NPB][64];
    int bid = blockIdx.x;
    int t = threadIdx.x;
    if ((bid & 7) != 7) {
        // ---- bucket role: ILP-4 scatter ----
        int vbid = bid - (bid >> 3);                 // bucket-block index
        int nbuck = gridDim.x - (gridDim.x >> 3);    // number of bucket blocks
        for (int c0 = vbid * 1024; c0 < E; c0 += nbuck * 1024) {
            int s[4], d[4]; unsigned wq[4]; bool ok[4];
#pragma unroll
            for (int k = 0; k < 4; ++k) {
                int e = c0 + t + k * 256;
                ok[k] = (e < E);
                if (ok[k]) {
                    s[k] = ei[e];
                    d[k] = ei[E + e];
                    wq[k] = (unsigned)(ew[e] * 1048576.0f + 0.5f);
                }
            }
#pragma unroll
            for (int k = 0; k < 4; ++k) {
                if (ok[k]) {
                    unsigned long long old =
                        atomicAdd(&cs[s[k]], (((unsigned long long)wq[k]) << 32) | 1ull);
                    unsigned pos = (unsigned)(old & 0xFFFFFFFFu);
                    if (pos < CAP) slots[(size_t)s[k] * CAP + pos] = d[k];
                }
            }
        }
        return;
    }
    // ---- hmu role ----
    int vh = bid >> 3;                 // 0..nh-1
    int nh = gridDim.x >> 3;
    for (int i = t; i < 64 * 64; i += 256) {
        int r = i >> 6, c = i & 63;
        sW3[r * 65 + c]  = W3[i];
        sW4c[r * 65 + c] = W4[r * 192 + 128 + c];
    }
    int local = t >> 6;   // 0..3
    int j = t & 63;       // feature
    float aj = a[j], bj = b[j], vaj = va[j], vbj = vb[j];
    __syncthreads();
    for (int n0 = vh * NPB; n0 < n_nodes; n0 += nh * NPB) {
        int n = n0 + local;
        bool okn = (n < n_nodes);
        smu[local][j] = okn ? mu[(size_t)n * 64 + j] : 0.f;
        __syncthreads();
        float acc = 0.f;
#pragma unroll
        for (int k = 0; k < 64; ++k) acc += smu[local][k] * sW3[j * 65 + k];
        float hm = fmaxf(acc, 0.f);
        srow[local][j] = hm;
        __syncthreads();
        float acc2 = 0.f;
#pragma unroll
        for (int o = 0; o < 64; ++o) acc2 += srow[local][o] * sW4c[j * 65 + o];
        if (okn) {
            float xv = x[n];
            float p = fmaxf(xv, 0.f), q = fmaxf(-xv, 0.f);
            base[(size_t)n * 64 + j] = p * aj + q * bj + hm;
            float hv = acc2 + p * vaj + q * vbj;
            unsigned u = __float_as_uint(hv);
            unsigned r = (u + 0x7FFFu + ((u >> 16) & 1u)) >> 16;  // RNE to bf16
            hc2[(size_t)n * 64 + j] = (unsigned short)r;
        }
        __syncthreads();
    }
}

// ---------- K2: pull-gather of bf16 hc2 + fused epilogue ----------
__global__ void __launch_bounds__(256) k_final(
    const unsigned short* __restrict__ hc2, const float* __restrict__ base,
    const unsigned long long* __restrict__ cs, const int* __restrict__ slots,
    const float* __restrict__ vs,
    float* __restrict__ out, int n_nodes) {
    int wave = threadIdx.x >> 6;
    int j = threadIdx.x & 63;
    int n = blockIdx.x * NPB + wave;
    if (n >= n_nodes) return;
    unsigned long long c = cs[n];
    int deg = (int)(unsigned)(c & 0xFFFFFFFFu);
    if (deg > CAP) deg = CAP;
    float sw = (float)(unsigned)(c >> 32) * (1.0f / 1048576.0f);
    const int* sl = slots + (size_t)n * CAP;
    float acc = 0.f;
    int i = 0;
    for (; i + 8 <= deg; i += 8) {
        int d0 = sl[i + 0], d1 = sl[i + 1], d2 = sl[i + 2], d3 = sl[i + 3];
        int d4 = sl[i + 4], d5 = sl[i + 5], d6 = sl[i + 6], d7 = sl[i + 7];
        unsigned u0 = hc2[(size_t)d0 * 64 + j];
        unsigned u1 = hc2[(size_t)d1 * 64 + j];
        unsigned u2 = hc2[(size_t)d2 * 64 + j];
        unsigned u3 = hc2[(size_t)d3 * 64 + j];
        unsigned u4 = hc2[(size_t)d4 * 64 + j];
        unsigned u5 = hc2[(size_t)d5 * 64 + j];
        unsigned u6 = hc2[(size_t)d6 * 64 + j];
        unsigned u7 = hc2[(size_t)d7 * 64 + j];
        acc += __uint_as_float(u0 << 16) + __uint_as_float(u1 << 16)
             + __uint_as_float(u2 << 16) + __uint_as_float(u3 << 16)
             + __uint_as_float(u4 << 16) + __uint_as_float(u5 << 16)
             + __uint_as_float(u6 << 16) + __uint_as_float(u7 << 16);
    }
    for (; i < deg; ++i) {
        unsigned u = hc2[(size_t)sl[i] * 64 + j];
        acc += __uint_as_float(u << 16);
    }
    float agg = fmaxf(sw * vs[j] + acc, 0.f);
    out[(size_t)n * 64 + j] = fmaxf(base[(size_t)n * 64 + j] + agg, 0.f);
}

extern "C" void kernel_launch(void* const* d_in, const int* in_sizes, int n_in,
                              void* d_out, int out_size, void* d_ws, size_t ws_size,
                              hipStream_t stream) {
    const float* mu = (const float*)d_in[0];
    const float* x  = (const float*)d_in[1];
    const int*   ei = (const int*)d_in[2];
    const float* ew = (const float*)d_in[3];
    const float* W1 = (const float*)d_in[4];
    const float* W2 = (const float*)d_in[5];
    const float* W3 = (const float*)d_in[6];
    const float* W4 = (const float*)d_in[7];
    float* out = (float*)d_out;

    const int N = in_sizes[1];       // 50000
    const int E = in_sizes[3];       // 1600000

    // workspace layout (d_ws is 8-byte aligned)
    unsigned long long* cs = (unsigned long long*)d_ws;        // N u64
    float* base = (float*)(cs + N);                            // N*64 f32
    unsigned short* hc2 = (unsigned short*)(base + (size_t)N * 64);  // N*64 bf16
    int* slots = (int*)(hc2 + (size_t)N * 64);                 // N*CAP int
    float* av  = (float*)(slots + (size_t)N * CAP);            // 64 x5 f32
    float* bv  = av + 64;
    float* vav = bv + 64;
    float* vbv = vav + 64;
    float* vsv = vbv + 64;

    (void)hipMemsetAsync(cs, 0, (size_t)N * 8, stream);

    k_prep<<<1, 64, 0, stream>>>(W1, W2, W4, av, bv, vav, vbv, vsv);

    // fused bucket+hmu: 2048 blocks, every 8th is hmu (256 hmu / 1792 bucket)
    k_mid<<<2048, 256, 0, stream>>>(mu, W3, W4, x, av, bv, vav, vbv,
                                    base, hc2, ei, ew, cs, slots, N, E);

    int fblocks = (N + NPB - 1) / NPB;
    k_final<<<fblocks, 256, 0, stream>>>(hc2, base, cs, slots, vsv, out, N);
}

// Round 5
// 290.203 us; speedup vs baseline: 1.4738x; 1.4738x over previous
//
#include <hip/hip_runtime.h>

// S2V GNN step:
//  out[n][j] = relu( base[n][j] + relu( sw[n]*vs[j] + sum_{e:src=n} hc2[dst_e][j] ) )
//  base = p*a + q*b + h_mu          (p,q = relu(+-x))
//  hc2  = h_mu@W4c.T + p*va + q*vb  (stored bf16)
//  sw   = sum of ew over out-edges  (carried in the counting u64 atomic, 2^20 fixed point)
// NOTE R4 lesson: do NOT fuse LDS-heavy GEMM with the scatter via block roles —
// the LDS allocation applies to all blocks and collapses scatter occupancy 74%->13%.

#define CAP 96     // bucket capacity; deg ~ Poisson(32), P(deg>=96) ~ 1e-19/node
#define NPB 4      // nodes (waves) per 256-thread block in k_final

// ---------- K0: tiny weight-derived vectors ----------
__global__ void k_prep(const float* __restrict__ W1, const float* __restrict__ W2,
                       const float* __restrict__ W4,
                       float* __restrict__ a, float* __restrict__ b,
                       float* __restrict__ va, float* __restrict__ vb,
                       float* __restrict__ vs) {
    __shared__ float sa[64], sb[64], sw[64];
    int j = threadIdx.x;  // 0..63
    float w1 = W1[j], w2 = W2[j];
    sa[j] = fmaxf(w1, 0.f);
    sb[j] = fmaxf(-w1, 0.f);
    sw[j] = fmaxf(w2, 0.f);
    __syncthreads();
    float s1 = 0.f, s2 = 0.f, s3 = 0.f;
#pragma unroll
    for (int o = 0; o < 64; ++o) {
        float w4a = W4[j * 192 + o];
        float w4b = W4[j * 192 + 64 + o];
        s1 += w4a * sa[o];
        s2 += w4a * sb[o];
        s3 += w4b * sw[o];
    }
    a[j] = sa[j]; b[j] = sb[j];
    va[j] = s1; vb[j] = s2; vs[j] = s3;
}

// ---------- K1: base = p*a+q*b+relu(mu@W3.T); hc2(bf16) = h_mu@W4c.T + p*va+q*vb ----------
__global__ void __launch_bounds__(256) k_hmu(
    const float* __restrict__ mu, const float* __restrict__ W3, const float* __restrict__ W4,
    const float* __restrict__ x,
    const float* __restrict__ a, const float* __restrict__ b,
    const float* __restrict__ va, const float* __restrict__ vb,
    float* __restrict__ base, unsigned short* __restrict__ hc2, int n_nodes) {
    __shared__ float sW3[64 * 65];
    __shared__ float sW4c[64 * 65];
    __shared__ float smu[NPB][64];
    __shared__ float srow[NPB][64];
    int t = threadIdx.x;
    for (int i = t; i < 64 * 64; i += 256) {
        int r = i >> 6, c = i & 63;
        sW3[r * 65 + c]  = W3[i];
        sW4c[r * 65 + c] = W4[r * 192 + 128 + c];
    }
    int local = t >> 6;   // 0..3
    int j = t & 63;       // feature
    float aj = a[j], bj = b[j], vaj = va[j], vbj = vb[j];
    __syncthreads();
    for (int n0 = blockIdx.x * NPB; n0 < n_nodes; n0 += gridDim.x * NPB) {
        int n = n0 + local;
        bool ok = (n < n_nodes);
        smu[local][j] = ok ? mu[(size_t)n * 64 + j] : 0.f;
        __syncthreads();
        float acc = 0.f;
#pragma unroll
        for (int k = 0; k < 64; ++k) acc += smu[local][k] * sW3[j * 65 + k];
        float hm = fmaxf(acc, 0.f);
        srow[local][j] = hm;
        __syncthreads();
        float acc2 = 0.f;
#pragma unroll
        for (int o = 0; o < 64; ++o) acc2 += srow[local][o] * sW4c[j * 65 + o];
        if (ok) {
            float xv = x[n];
            float p = fmaxf(xv, 0.f), q = fmaxf(-xv, 0.f);
            base[(size_t)n * 64 + j] = p * aj + q * bj + hm;
            float hv = acc2 + p * vaj + q * vbj;
            unsigned u = __float_as_uint(hv);
            unsigned r = (u + 0x7FFFu + ((u >> 16) & 1u)) >> 16;  // RNE to bf16
            hc2[(size_t)n * 64 + j] = (unsigned short)r;
        }
        __syncthreads();
    }
}

// ---------- K2: one pass over edges, 1 u64 atomic + 1 int store per edge ----------
__global__ void k_bucket(const int* __restrict__ ei, const float* __restrict__ ew,
                         unsigned long long* __restrict__ cs, int* __restrict__ slots, int E) {
    int e = blockIdx.x * blockDim.x + threadIdx.x;
    if (e >= E) return;
    int s = ei[e];
    int d = ei[E + e];
    unsigned wq = (unsigned)(ew[e] * 1048576.0f + 0.5f);
    unsigned long long old =
        atomicAdd(&cs[s], (((unsigned long long)wq) << 32) | 1ull);
    unsigned pos = (unsigned)(old & 0xFFFFFFFFu);
    if (pos < CAP) slots[(size_t)s * CAP + pos] = d;
}

// ---------- K3: pull-gather of bf16 hc2 + fused epilogue ----------
__global__ void __launch_bounds__(256) k_final(
    const unsigned short* __restrict__ hc2, const float* __restrict__ base,
    const unsigned long long* __restrict__ cs, const int* __restrict__ slots,
    const float* __restrict__ vs,
    float* __restrict__ out, int n_nodes) {
    int wave = threadIdx.x >> 6;
    int j = threadIdx.x & 63;
    int n = blockIdx.x * NPB + wave;
    if (n >= n_nodes) return;
    unsigned long long c = cs[n];
    int deg = (int)(unsigned)(c & 0xFFFFFFFFu);
    if (deg > CAP) deg = CAP;
    float sw = (float)(unsigned)(c >> 32) * (1.0f / 1048576.0f);
    const int* sl = slots + (size_t)n * CAP;
    float acc = 0.f;
    int i = 0;
    for (; i + 8 <= deg; i += 8) {
        int d0 = sl[i + 0], d1 = sl[i + 1], d2 = sl[i + 2], d3 = sl[i + 3];
        int d4 = sl[i + 4], d5 = sl[i + 5], d6 = sl[i + 6], d7 = sl[i + 7];
        unsigned u0 = hc2[(size_t)d0 * 64 + j];
        unsigned u1 = hc2[(size_t)d1 * 64 + j];
        unsigned u2 = hc2[(size_t)d2 * 64 + j];
        unsigned u3 = hc2[(size_t)d3 * 64 + j];
        unsigned u4 = hc2[(size_t)d4 * 64 + j];
        unsigned u5 = hc2[(size_t)d5 * 64 + j];
        unsigned u6 = hc2[(size_t)d6 * 64 + j];
        unsigned u7 = hc2[(size_t)d7 * 64 + j];
        acc += __uint_as_float(u0 << 16) + __uint_as_float(u1 << 16)
             + __uint_as_float(u2 << 16) + __uint_as_float(u3 << 16)
             + __uint_as_float(u4 << 16) + __uint_as_float(u5 << 16)
             + __uint_as_float(u6 << 16) + __uint_as_float(u7 << 16);
    }
    for (; i < deg; ++i) {
        unsigned u = hc2[(size_t)sl[i] * 64 + j];
        acc += __uint_as_float(u << 16);
    }
    float agg = fmaxf(sw * vs[j] + acc, 0.f);
    out[(size_t)n * 64 + j] = fmaxf(base[(size_t)n * 64 + j] + agg, 0.f);
}

extern "C" void kernel_launch(void* const* d_in, const int* in_sizes, int n_in,
                              void* d_out, int out_size, void* d_ws, size_t ws_size,
                              hipStream_t stream) {
    const float* mu = (const float*)d_in[0];
    const float* x  = (const float*)d_in[1];
    const int*   ei = (const int*)d_in[2];
    const float* ew = (const float*)d_in[3];
    const float* W1 = (const float*)d_in[4];
    const float* W2 = (const float*)d_in[5];
    const float* W3 = (const float*)d_in[6];
    const float* W4 = (const float*)d_in[7];
    float* out = (float*)d_out;

    const int N = in_sizes[1];       // 50000
    const int E = in_sizes[3];       // 1600000

    // workspace layout (d_ws is 8-byte aligned)
    unsigned long long* cs = (unsigned long long*)d_ws;              // N u64
    float* base = (float*)(cs + N);                                  // N*64 f32
    unsigned short* hc2 = (unsigned short*)(base + (size_t)N * 64);  // N*64 bf16
    int* slots = (int*)(hc2 + (size_t)N * 64);                       // N*CAP int
    float* av  = (float*)(slots + (size_t)N * CAP);                  // 64 x5 f32
    float* bv  = av + 64;
    float* vav = bv + 64;
    float* vbv = vav + 64;
    float* vsv = vbv + 64;

    (void)hipMemsetAsync(cs, 0, (size_t)N * 8, stream);

    k_prep<<<1, 64, 0, stream>>>(W1, W2, W4, av, bv, vav, vbv, vsv);
    k_hmu<<<1024, 256, 0, stream>>>(mu, W3, W4, x, av, bv, vav, vbv, base, hc2, N);

    int eblocks = (E + 255) / 256;
    k_bucket<<<eblocks, 256, 0, stream>>>(ei, ew, cs, slots, E);

    int fblocks = (N + NPB - 1) / NPB;
    k_final<<<fblocks, 256, 0, stream>>>(hc2, base, cs, slots, vsv, out, N);
}